// Round 6
// baseline (1623.054 us; speedup 1.0000x reference)
//
#include <hip/hip_runtime.h>
#include <math.h>

#define MU_F 0.1f
#define SHRINK_F 0.01f   // LMBD * MU
#define BN_EPS_F 1e-5f

typedef _Float16 half_t;
typedef _Float16 half8 __attribute__((ext_vector_type(8)));
typedef float f32x4 __attribute__((ext_vector_type(4)));

// async global->LDS, 16B per lane. LDS dest is wave-uniform base + lane*16.
__device__ __forceinline__ void gll16(const half_t* g, half_t* l) {
    __builtin_amdgcn_global_load_lds(
        (const __attribute__((address_space(1))) void*)g,
        (__attribute__((address_space(3))) void*)l, 16, 0, 0);
}

// counted-vmcnt wait + raw barrier (verified idiom; rule #18 hygiene).
#define VM_WAIT_BARRIER(N) do {                                   \
    asm volatile("s_waitcnt vmcnt(" #N ")" ::: "memory");         \
    __builtin_amdgcn_s_barrier();                                 \
    __builtin_amdgcn_sched_barrier(0);                            \
} while (0)

// ---------------------------------------------------------------------------
// MFMA implicit-GEMM conv, v6: L2-demand reduction.
// Model (fits r0-r5): time = L2 bytes / ~4 TB/s. Old: A 226 MB + B 226 MB.
//  - A (weights): contiguous repack [ci-chunk][tap][co][32ci]; per chunk one
//    8 KB sequential block via 2 gll16/wave into a 3-slot LDS ring (24 KB),
//    counted vmcnt(6): chunk k+2 in flight across the barrier.
//  - B (activations): per-lane VGPR loads THROUGH L1, tap-INNERMOST chunk
//    order (flat = cc*9 + tap) -> consecutive taps hit the same cache lines
//    (per-ci-chunk unique window ~13 KB fits 32 KB L1 across all 9 taps).
//    B L2 traffic ~226 -> ~40 MB. No B in LDS; rb regs double-buffered with
//    STATIC unroll-2 indexing (rule #20).
// block = 128co x 128px (batch folded: NPX = 32*28*28 = 25088, exact tiles),
// 4 waves (2co x 2px) of 64x64, K-chunk 32, 16 MFMA : 2 gll16 : 4 B-loads.
// MODE 0: fwd conv stride S pad PAD; MODE 1: convT s1 (pad 1).
// edge_defer/out2F: Gram-path plumbing (see round 5).
// Frag layout (16x16x32): A row=l&15, k=(l>>4)*8+j ; B col=l&15 same k;
// C/D col=l&15, row=(l>>4)*4+reg  [m89-verified].
// ---------------------------------------------------------------------------
template<int KS, int S, int PAD, int MODE>
__global__ __launch_bounds__(256, 2)
void conv_big(const half_t* __restrict__ Ag, const half_t* __restrict__ Xh,
              float* __restrict__ outF, half_t* __restrict__ outH,
              const half_t* __restrict__ auxH, const float* __restrict__ auxF,
              int CA, int Cout, int Hin, int Win, int Hout, int Wout, int ptiles,
              float alpha, float beta, float delta, int relu1,
              const float* __restrict__ pscale, const float* __restrict__ pbias,
              const float* __restrict__ aux3, int relu2,
              const half_t* __restrict__ zpg, int edge_defer,
              float* __restrict__ out2F)
{
    __shared__ __align__(16) half_t sm[3 * 4096];   // 3-slot A ring, 8 KB/slot

    const int tid = threadIdx.x;
    const int wv = tid >> 6, ln = tid & 63;
    const int co0 = blockIdx.y * 128;
    const int wco = (wv & 1) * 64, wpx = (wv >> 1) * 64;
    (void)ptiles;

    // bijective XCD swizzle (m204)
    int bx;
    {
        const int nwg = gridDim.x;
        const int q = nwg >> 3, r8 = nwg & 7;
        const int xcd = blockIdx.x & 7, idx = blockIdx.x >> 3;
        bx = (xcd < r8 ? xcd * (q + 1) : r8 * (q + 1) + (xcd - r8) * q) + idx;
    }
    const int p0 = bx * 128;

    const int PHW1 = Hout * Wout;
    const int NPX  = PHW1 * 32;

    const int r   = tid >> 2;            // co row within 64-row DMA pass
    const int s4  = tid & 3;             // 16B slot
    const int asl = (s4 ^ ((r >> 1) & 3)) << 3;   // pre-swizzled src slot (halves)

    const int fr = ln & 15, q8 = ln >> 4;
    const int koh = q8 * 8;              // k-offset (halves) of this lane's frag
    const int sx  = (q8 ^ ((fr >> 1) & 3)) << 3;  // swizzled ds_read slot
    const int rdA = (wco + fr) * 32 + sx;

    const int cpt   = CA >> 5;           // ci-chunks per tap (4 or 8)
    const int ntap  = KS * KS;
    const int total = ntap * cpt;        // even at every call site

    // per-lane output px geometry (shared by B loads and epilogue)
    int eph[4], epw[4], en2[4]; size_t ebase[4]; bool evalid[4];
#pragma unroll
    for (int t2 = 0; t2 < 4; ++t2) {
        int px = p0 + wpx + t2 * 16 + fr;
        evalid[t2] = px < NPX;
        int pc = evalid[t2] ? px : 0;
        en2[t2] = pc / PHW1; int rem = pc - en2[t2] * PHW1;
        eph[t2] = rem / Wout; epw[t2] = rem - eph[t2] * Wout;
        ebase[t2] = (size_t)en2[t2] * Hin * Win;
    }

    // A: chunk flat -> contiguous 8 KB block at flat*Cout*32
    auto issueA = [&](int flat, half_t* dst) {
        const size_t base = ((size_t)flat * Cout + co0) * 32;
        gll16(Ag + base + (size_t)r * 32 + asl,        dst +        tid * 8);
        gll16(Ag + base + (size_t)(r + 64) * 32 + asl, dst + 2048 + tid * 8);
    };

    // B: per-lane half8 loads through L1 (tap-inner => L1 line reuse)
    auto loadB = [&](int flat, half8 (&rb)[4]) {
        int cc, ti;
        if (KS == 1) { cc = flat; ti = 0; }
        else         { cc = (flat * 57) >> 9; ti = flat - 9 * cc; }  // /9, flat<72
        const int kh = (KS == 3) ? ((ti * 11) >> 5) : 0;             // /3, ti<9
        const int kw = (KS == 3) ? (ti - 3 * kh) : 0;
        const int c0h = (cc << 5) + koh;
#pragma unroll
        for (int t2 = 0; t2 < 4; ++t2) {
            int ihh, iww; bool ok = evalid[t2];
            if (MODE == 0) { ihh = eph[t2] * S - PAD + kh; iww = epw[t2] * S - PAD + kw; }
            else           { ihh = eph[t2] + PAD - kh;     iww = epw[t2] + PAD - kw; }
            ok = ok && (unsigned)ihh < (unsigned)Hin && (unsigned)iww < (unsigned)Win;
            long long soff = ((long long)ebase[t2] + (long long)ihh * Win + iww) * CA + c0h;
            const half_t* p = ok ? (Xh + soff) : zpg;
            rb[t2] = *(const half8*)p;
        }
    };

    f32x4 acc[4][4] = {};
    half8 rb0[4], rb1[4];

    // prologue: A(0),A(1) in flight; B(0) in regs; wait A(0) (8 out -> 6)
    issueA(0, sm);
    issueA(1, sm + 4096);
    __builtin_amdgcn_sched_barrier(0);
    loadB(0, rb0);
    VM_WAIT_BARRIER(6);

    // one pipeline step; rbR = this chunk's B, rbW = next chunk's B buffer.
    auto step = [&](int k, half8 (&rbR)[4], half8 (&rbW)[4]) {
        half_t* slot = sm + (k % 3) * 4096;
        if (k + 2 < total) issueA(k + 2, sm + ((k + 2) % 3) * 4096);
        __builtin_amdgcn_sched_barrier(0);   // pin A-issue before B loads
        if (k + 1 < total) loadB(k + 1, rbW);
        half8 fa[4];
#pragma unroll
        for (int m = 0; m < 4; ++m)
            fa[m] = *(const half8*)(slot + rdA + m * 512);
#pragma unroll
        for (int m = 0; m < 4; ++m)
#pragma unroll
            for (int t2 = 0; t2 < 4; ++t2)
                acc[m][t2] = __builtin_amdgcn_mfma_f32_16x16x32_f16(fa[m], rbR[t2], acc[m][t2], 0, 0, 0);
        // worst-case queue after MFMA's implicit B-wait: A(k+2)=2 + B(k+1)=4
        // vmcnt(6) guarantees A(k+1) (and B(k)) retired before the barrier.
        if (k + 1 < total) VM_WAIT_BARRIER(6);
    };

    for (int k = 0; k < total; k += 2) {   // total is even everywhere
        step(k,     rb0, rb1);
        step(k + 1, rb1, rb0);
    }

    // epilogue
    const int rg = ln >> 4;
#pragma unroll
    for (int t = 0; t < 4; ++t) {
        if (!evalid[t]) continue;
        int oh = eph[t], ow = epw[t], n2 = en2[t];
        size_t ghwc = ((size_t)(n2 * Hout + oh) * Wout + ow) * Cout;
        bool defer = edge_defer && (oh == 0 || ow == 0);
#pragma unroll
        for (int m = 0; m < 4; ++m) {
#pragma unroll
            for (int rr = 0; rr < 4; ++rr) {
                int co_l = co0 + wco + m * 16 + rg * 4 + rr;
                size_t fidx = ((size_t)(n2 * Cout + co_l) * Hout + oh) * Wout + ow;
                float av = alpha * acc[m][t][rr];
                if (out2F) out2F[fidx] = av;
                float v = av + delta;
                if (auxH) v += beta * (float)auxH[ghwc + co_l];
                if (auxF) v += beta * auxF[fidx];
                if (!defer) {
                    if (relu1) v = fmaxf(v, 0.f);
                    if (pscale) v = pscale[co_l] * v + pbias[co_l];
                    if (aux3) v += aux3[fidx];
                    if (relu2) v = fmaxf(v, 0.f);
                }
                if (outH) outH[ghwc + co_l] = (half_t)v;
                else      outF[fidx] = v;
            }
        }
    }
}

// pack weights into the contiguous MFMA layout [ci-chunk][tap][co][32ci]
// (and transpose variant [co-chunk][tap][ci][32co] for convT).
template<int KT>
__global__ __launch_bounds__(256)
void pack_w(const float* __restrict__ W, half_t* __restrict__ Wh,
            half_t* __restrict__ WTh, int Cin, int Cout, int do_norm)
{
    __shared__ float red[256];
    int co = blockIdx.x, tid = threadIdx.x;
    int CK = Cin * KT;
    const float* w = W + (size_t)co * CK;
    float inv = 1.f;
    if (do_norm) {
        float s = 0.f;
        for (int i = tid; i < CK; i += 256) { float v = w[i]; s += v * v; }
        red[tid] = s; __syncthreads();
        for (int o = 128; o > 0; o >>= 1) {
            if (tid < o) red[tid] += red[tid + o];
            __syncthreads();
        }
        inv = 1.f / (sqrtf(red[0]) + 1e-12f);
    }
    for (int i = tid; i < CK; i += 256) {
        int ci = i / KT, tap = i - ci * KT;
        half_t h = (half_t)(w[i] * inv);
        Wh[(((size_t)(ci >> 5) * KT + tap) * Cout + co) * 32 + (ci & 31)] = h;
        if (WTh) WTh[(((size_t)(co >> 5) * KT + tap) * Cin + ci) * 32 + (co & 31)] = h;
    }
}

// ---------------------------------------------------------------------------
// Gram precompute (see round 5): Gp in the contiguous conv layout
// [b-chunk][tap][co][32b]; edge tensors unchanged.
// ---------------------------------------------------------------------------
__global__ __launch_bounds__(256)
void gram_kernel(const half_t* __restrict__ Wh, half_t* __restrict__ Gp,
                 half_t* __restrict__ ChT, half_t* __restrict__ CwT,
                 half_t* __restrict__ CcT)
{
    // Wh here is the ORIGINAL [co][tap][ci] layout (Wraw below), ci<128.
    __shared__ float Wa[9 * 128];
    int co = blockIdx.x, b = threadIdx.x;
    for (int i = b; i < 9 * 128; i += 256) Wa[i] = (float)Wh[(size_t)co * 9 * 128 + i];
    __syncthreads();
    const half_t* Wb = Wh + (size_t)b * 9 * 128;
    auto dot = [&](int tA, int tB) {
        float s = 0.f;
        for (int c = 0; c < 128; ++c) s += Wa[tA * 128 + c] * (float)Wb[tB * 128 + c];
        return s;
    };
    auto lo = [](int t) { return (t == 2) ? 2 : 0; };
    auto hi = [](int t) { return (t == 1) ? 3 : ((t == 2) ? 3 : 1); };
    for (int th = 0; th < 3; ++th)
        for (int tw = 0; tw < 3; ++tw) {
            float s = 0.f;
            for (int kh = lo(th); kh < hi(th); ++kh)
                for (int kw = lo(tw); kw < hi(tw); ++kw)
                    s += dot(kh * 3 + kw, (kh + 2 - 2 * th) * 3 + (kw + 2 - 2 * tw));
            Gp[(((size_t)(b >> 5) * 9 + th * 3 + tw) * 256 + co) * 32 + (b & 31)] = (half_t)s;
        }
    for (int tw = 0; tw < 3; ++tw) {
        float s = 0.f, s2 = 0.f;
        for (int k = lo(tw); k < hi(tw); ++k) {
            s  += dot(k, k + 2 - 2 * tw);
            s2 += dot(k * 3, (k + 2 - 2 * tw) * 3);
        }
        ChT[((size_t)tw * 256 + b) * 256 + co] = (half_t)s;
        CwT[((size_t)tw * 256 + b) * 256 + co] = (half_t)s2;
    }
    CcT[(size_t)b * 256 + co] = (half_t)dot(0, 0);
}

// raw [co][tap][ci] normalized pack (input for gram_kernel only)
__global__ __launch_bounds__(256)
void pack_raw(const float* __restrict__ W, half_t* __restrict__ Wr, int CK)
{
    __shared__ float red[256];
    int co = blockIdx.x, tid = threadIdx.x;
    const float* w = W + (size_t)co * CK;
    float s = 0.f;
    for (int i = tid; i < CK; i += 256) { float v = w[i]; s += v * v; }
    red[tid] = s; __syncthreads();
    for (int o = 128; o > 0; o >>= 1) {
        if (tid < o) red[tid] += red[tid + o];
        __syncthreads();
    }
    float inv = 1.f / (sqrtf(red[0]) + 1e-12f);
    for (int i = tid; i < CK; i += 256) {
        int ci = i / 9, tap = i - ci * 9;
        Wr[((size_t)co * 9 + tap) * (CK / 9) + ci] = (half_t)(w[i] * inv);
    }
}

__global__ __launch_bounds__(256)
void edge_fix(const half_t* __restrict__ a, half_t* out,
              const half_t* __restrict__ ChT, const half_t* __restrict__ CwT,
              const half_t* __restrict__ CcT,
              const float* __restrict__ ps, const float* __restrict__ pb)
{
    int i = blockIdx.x, n = blockIdx.y, co = threadIdx.x;
    int oh, ow;
    if (i < 28) { oh = 0; ow = i; } else { oh = i - 27; ow = 0; }
    float corr = 0.f;
    if (oh == 0) {
        for (int kw = 0; kw < 3; ++kw) {
            int pw = ow - 1 + kw;
            if ((unsigned)pw < 28u) {
                const half_t* ap = a + ((size_t)(n * 28 + 0) * 28 + pw) * 256;
                const half_t* cp = ChT + (size_t)kw * 256 * 256 + co;
                for (int b2 = 0; b2 < 256; ++b2)
                    corr += (float)cp[(size_t)b2 * 256] * (float)ap[b2];
            }
        }
    }
    if (ow == 0) {
        for (int kh = 0; kh < 3; ++kh) {
            int ph = oh - 1 + kh;
            if ((unsigned)ph < 28u) {
                const half_t* ap = a + ((size_t)(n * 28 + ph) * 28 + 0) * 256;
                const half_t* cp = CwT + (size_t)kh * 256 * 256 + co;
                for (int b2 = 0; b2 < 256; ++b2)
                    corr += (float)cp[(size_t)b2 * 256] * (float)ap[b2];
            }
        }
    }
    if (oh == 0 && ow == 0) {
        const half_t* ap = a + ((size_t)(n * 28) * 28) * 256;
        for (int b2 = 0; b2 < 256; ++b2)
            corr -= (float)CcT[(size_t)b2 * 256 + co] * (float)ap[b2];
    }
    size_t idx = ((size_t)(n * 28 + oh) * 28 + ow) * 256 + co;
    float v = (float)out[idx] + MU_F * corr;
    v = fmaxf(v, 0.f);
    if (ps) v = ps[co] * v + pb[co];
    out[idx] = (half_t)v;
}

__global__ __launch_bounds__(256)
void tx_kernel(const float* __restrict__ x, half_t* __restrict__ xTh)
{
    __shared__ __align__(16) half_t tl[56 * 136];
    int h = blockIdx.x, n = blockIdx.y, tid = threadIdx.x;
    for (int it = 0; it < 28; ++it) {
        int id = tid + it * 256;
        int c = id / 56, w0 = id - c * 56;
        tl[w0 * 136 + c] = (half_t)x[(((size_t)n * 128 + c) * 56 + h) * 56 + w0];
    }
    __syncthreads();
    if (tid < 224) {
        int w0 = tid >> 2, part = tid & 3;
        size_t base = (((size_t)n * 56 + h) * 56 + w0) * 128 + part * 32;
#pragma unroll
        for (int j = 0; j < 4; ++j)
            *(half8*)(xTh + base + j * 8) = *(const half8*)(tl + w0 * 136 + part * 32 + j * 8);
    }
}

__global__ __launch_bounds__(256)
void comb_kernel(const half_t* __restrict__ c, const half_t* __restrict__ p,
                 half_t* __restrict__ a, float w1, float w2, int n8)
{
    int i = blockIdx.x * 256 + threadIdx.x;
    if (i >= n8) return;
    half8 cv = ((const half8*)c)[i];
    half8 pv = ((const half8*)p)[i];
    half8 rres;
#pragma unroll
    for (int j = 0; j < 8; ++j) rres[j] = (half_t)(w1 * (float)cv[j] + w2 * (float)pv[j]);
    ((half8*)a)[i] = rres;
}

__global__ __launch_bounds__(256)
void bn_prep_kernel(const float* __restrict__ g, const float* __restrict__ b,
                    const float* __restrict__ m, const float* __restrict__ v,
                    float* __restrict__ s, float* __restrict__ t, int C)
{
    int i = blockIdx.x * 256 + threadIdx.x;
    if (i < C) {
        float sc = g[i] * rsqrtf(v[i] + BN_EPS_F);
        s[i] = sc; t[i] = b[i] - m[i] * sc;
    }
}

__global__ __launch_bounds__(128)
void zfill_kernel(half_t* __restrict__ p)
{
    p[threadIdx.x] = (half_t)0.f;
}

extern "C" void kernel_launch(void* const* d_in, const int* in_sizes, int n_in,
                              void* d_out, int out_size, void* d_ws, size_t ws_size,
                              hipStream_t stream)
{
    (void)in_sizes; (void)n_in; (void)out_size;
    const float* x    = (const float*)d_in[0];
    const float* W1   = (const float*)d_in[1];
    const float* W2   = (const float*)d_in[2];
    const float* Wsc  = (const float*)d_in[3];
    const float* bn1g = (const float*)d_in[4];
    const float* bn1b = (const float*)d_in[5];
    const float* bn1m = (const float*)d_in[6];
    const float* bn1v = (const float*)d_in[7];
    const float* bn2g = (const float*)d_in[8];
    const float* bn2b = (const float*)d_in[9];
    const float* bn2m = (const float*)d_in[10];
    const float* bn2v = (const float*)d_in[11];
    const float* bscg = (const float*)d_in[12];
    const float* bscb = (const float*)d_in[13];
    const float* bscm = (const float*)d_in[14];
    const float* bscv = (const float*)d_in[15];

    const size_t NB = (size_t)32 * 256 * 28 * 28;
    const size_t NX = (size_t)32 * 128 * 56 * 56;

    char* base = (char*)d_ws;
    size_t off = 0;
    auto alloc = [&](size_t nbytes) -> void* {
        void* r = base + off;
        off = (off + nbytes + 255) & ~(size_t)255;
        return r;
    };
    half_t* Wh1  = (half_t*)alloc(294912 * 2);
    half_t* Wr1  = (half_t*)alloc(294912 * 2);   // raw [co][tap][ci] for gram
    half_t* Wh2  = (half_t*)alloc(589824 * 2);
    half_t* WTh2 = (half_t*)alloc(589824 * 2);
    half_t* Wsch = (half_t*)alloc(32768 * 2);
    half_t* Gph  = (half_t*)alloc(589824 * 2);
    half_t* ChT  = (half_t*)alloc(196608 * 2);
    half_t* CwT  = (half_t*)alloc(196608 * 2);
    half_t* CcT  = (half_t*)alloc(65536 * 2);
    float* bn1s = (float*)alloc(256 * 4);  float* bn1t = (float*)alloc(256 * 4);
    float* bn2s = (float*)alloc(256 * 4);  float* bn2t = (float*)alloc(256 * 4);
    float* bscs = (float*)alloc(256 * 4);  float* bsct = (float*)alloc(256 * 4);
    half_t* zpg  = (half_t*)alloc(256);
    half_t* xTh  = (half_t*)alloc(NX * 2);
    half_t* Pa   = (half_t*)alloc(NB * 2);
    half_t* Pb   = (half_t*)alloc(NB * 2);
    half_t* Pc   = (half_t*)alloc(NB * 2);
    half_t* Py   = (half_t*)alloc(NB * 2);
    half_t* r28h = (half_t*)alloc(NB * 2);
    float*  scF  = (float*)alloc(NB * 4);
    if (off > ws_size) return;

    float*  cxF = (float*)Py;    // fp32 NCHW cache, over Py+r28h (dead in stage A)
    half_t* Pd  = (half_t*)xTh;  // stage-B temp, over xTh (dead in stage B)

    float* outp = (float*)d_out;

    double t = 1.0; float al[3];
    for (int i = 0; i < 3; ++i) {
        double tn = (1.0 + sqrt(1.0 + 4.0 * t * t)) / 2.0;
        al[i] = (float)((t - 1.0) / tn); t = tn;
    }

    const dim3 blk(256);
    const dim3 cblk(256);
    const dim3 gB(196, 2, 1);
    const dim3 gE(55, 32, 1);
    const int n8 = (int)(NB / 8);
    const dim3 gC((n8 + 255) / 256);
    const float* NF = nullptr;
    const half_t* NH = nullptr;
    float* NFo = nullptr;
    half_t* NHo = nullptr;

    pack_w<9><<<256, blk, 0, stream>>>(W1, Wh1, nullptr, 128, 256, 1);
    pack_raw<<<256, blk, 0, stream>>>(W1, Wr1, 128 * 9);
    pack_w<9><<<256, blk, 0, stream>>>(W2, Wh2, WTh2, 256, 256, 1);
    pack_w<1><<<256, blk, 0, stream>>>(Wsc, Wsch, nullptr, 128, 256, 0);
    gram_kernel<<<256, blk, 0, stream>>>(Wr1, Gph, ChT, CwT, CcT);
    bn_prep_kernel<<<1, blk, 0, stream>>>(bn1g, bn1b, bn1m, bn1v, bn1s, bn1t, 256);
    bn_prep_kernel<<<1, blk, 0, stream>>>(bn2g, bn2b, bn2m, bn2v, bn2s, bn2t, 256);
    bn_prep_kernel<<<1, blk, 0, stream>>>(bscg, bscb, bscm, bscv, bscs, bsct, 256);
    zfill_kernel<<<1, dim3(128), 0, stream>>>(zpg);
    tx_kernel<<<dim3(56, 32), blk, 0, stream>>>(x, xTh);

    // ============ Stage A: dict_conv(x, W1, stride 2) — Gram form ==========
    conv_big<3,2,1,0><<<gB, cblk, 0, stream>>>(Wh1, xTh, NFo, Pa, NH, NF,
        128, 256, 56, 56, 28, 28, 196, MU_F, 0.f, -SHRINK_F, 1, NF, NF, NF, 0, zpg, 0, cxF);
    conv_big<1,2,0,0><<<gB, cblk, 0, stream>>>(Wsch, xTh, scF, NHo, NH, NF,
        128, 256, 56, 56, 28, 28, 196, 1.f, 0.f, 0.f, 0, bscs, bsct, NF, 0, zpg, 0, NFo);

    conv_big<3,1,1,0><<<gB, cblk, 0, stream>>>(Gph, Pa, NFo, Pb, Pa, cxF,
        256, 256, 28, 28, 28, 28, 196, -MU_F, 1.f, -SHRINK_F, 1, NF, NF, NF, 0, zpg, 1, NFo);
    edge_fix<<<gE, cblk, 0, stream>>>(Pa, Pb, ChT, CwT, CcT, NF, NF);

    comb_kernel<<<gC, blk, 0, stream>>>(Pb, Pa, Pc, 1.f + al[1], -al[1], n8);
    conv_big<3,1,1,0><<<gB, cblk, 0, stream>>>(Gph, Pc, NFo, Pa, Pc, cxF,
        256, 256, 28, 28, 28, 28, 196, -MU_F, 1.f, -SHRINK_F, 1, NF, NF, NF, 0, zpg, 1, NFo);
    edge_fix<<<gE, cblk, 0, stream>>>(Pc, Pa, ChT, CwT, CcT, NF, NF);

    comb_kernel<<<gC, blk, 0, stream>>>(Pa, Pb, Pc, 1.f + al[2], -al[2], n8);
    conv_big<3,1,1,0><<<gB, cblk, 0, stream>>>(Gph, Pc, NFo, Pb, Pc, cxF,
        256, 256, 28, 28, 28, 28, 196, -MU_F, 1.f, -SHRINK_F, 1, bn1s, bn1t, NF, 0, zpg, 1, NFo);
    edge_fix<<<gE, cblk, 0, stream>>>(Pc, Pb, ChT, CwT, CcT, bn1s, bn1t);

    // ================= Stage B: dict_conv(y1=Pb, W2, stride 1) =============
    conv_big<3,1,1,0><<<gB, cblk, 0, stream>>>(Wh2, Pb, NFo, Pa, NH, NF,
        256, 256, 28, 28, 28, 28, 196, MU_F, 0.f, -SHRINK_F, 1, NF, NF, NF, 0, zpg, 0, NFo);

    conv_big<3,1,1,1><<<gB, cblk, 0, stream>>>(WTh2, Pa, NFo, r28h, Pb, NF,
        256, 256, 28, 28, 28, 28, 196, -1.f, 1.f, 0.f, 0, NF, NF, NF, 0, zpg, 0, NFo);
    conv_big<3,1,1,0><<<gB, cblk, 0, stream>>>(Wh2, r28h, NFo, Pd, Pa, NF,
        256, 256, 28, 28, 28, 28, 196, MU_F, 1.f, -SHRINK_F, 1, NF, NF, NF, 0, zpg, 0, NFo);

    comb_kernel<<<gC, blk, 0, stream>>>(Pd, Pa, Pc, 1.f + al[1], -al[1], n8);
    conv_big<3,1,1,1><<<gB, cblk, 0, stream>>>(WTh2, Pc, NFo, r28h, Pb, NF,
        256, 256, 28, 28, 28, 28, 196, -1.f, 1.f, 0.f, 0, NF, NF, NF, 0, zpg, 0, NFo);
    conv_big<3,1,1,0><<<gB, cblk, 0, stream>>>(Wh2, r28h, NFo, Pa, Pc, NF,
        256, 256, 28, 28, 28, 28, 196, MU_F, 1.f, -SHRINK_F, 1, NF, NF, NF, 0, zpg, 0, NFo);

    comb_kernel<<<gC, blk, 0, stream>>>(Pa, Pd, Pc, 1.f + al[2], -al[2], n8);
    conv_big<3,1,1,1><<<gB, cblk, 0, stream>>>(WTh2, Pc, NFo, r28h, Pb, NF,
        256, 256, 28, 28, 28, 28, 196, -1.f, 1.f, 0.f, 0, NF, NF, NF, 0, zpg, 0, NFo);
    conv_big<3,1,1,0><<<gB, cblk, 0, stream>>>(Wh2, r28h, outp, NHo, Pc, NF,
        256, 256, 28, 28, 28, 28, 196, MU_F, 1.f, -SHRINK_F, 1, bn2s, bn2t, scF, 1, zpg, 0, NFo);
}